// Round 11
// baseline (97.029 us; speedup 1.0000x reference)
//
#include <hip/hip_runtime.h>
#include <math.h>

#define NN 4096
#define CC 16
#define DSP 2048
#define ED 300
#define HD 512

typedef __attribute__((ext_vector_type(8))) short short8;
typedef __attribute__((ext_vector_type(4))) float f32x4;

#define MFMA16(a, b, c) __builtin_amdgcn_mfma_f32_16x16x32_bf16((a), (b), (c), 0, 0, 0)

__device__ __forceinline__ unsigned short f2bf(float x) {
    unsigned u = __builtin_bit_cast(unsigned, x);
    u += 0x7FFFu + ((u >> 16) & 1u);   // RNE
    return (unsigned short)(u >> 16);
}

__device__ __forceinline__ float bf2f(unsigned short u) {
    return __builtin_bit_cast(float, (unsigned)u << 16);
}

__device__ __forceinline__ void gl_lds16(const void* g, void* l) {
    __builtin_amdgcn_global_load_lds(
        (const __attribute__((address_space(1))) unsigned*)g,
        (__attribute__((address_space(3))) unsigned*)l, 16, 0, 0);
}

__device__ __forceinline__ void pack8(unsigned short* dst, float4 a, float4 b) {
    unsigned short v[8] = { f2bf(a.x), f2bf(a.y), f2bf(a.z), f2bf(a.w),
                            f2bf(b.x), f2bf(b.y), f2bf(b.z), f2bf(b.w) };
    *(short8*)dst = *(short8*)v;
}

// ---------------------------------------------------------------------------
// Kernel 1: weight prep + span gather + length prefix-scan (+ticket zero).
// ---------------------------------------------------------------------------
__global__ __launch_bounds__(256) void prep_gather_scan(
    const float* __restrict__ W1,
    const float* __restrict__ span,
    const int*   __restrict__ lidx,
    const int*   __restrict__ clens,
    unsigned short* __restrict__ W1sT,
    unsigned short* __restrict__ w1ef,
    unsigned short* __restrict__ A16,
    int*            __restrict__ off,      // [4097], off[4096] = total
    unsigned*       __restrict__ ticket)
{
    const int bid = blockIdx.x, tid = threadIdx.x;

    if (bid == 4432) {   // scan block
        if (tid == 0) *ticket = 0u;        // re-zero every call (graph replay)
        __shared__ int ls[256];
        int myl[16];
        int msum = 0;
#pragma unroll
        for (int j = 0; j < 16; ++j) {
            int bk = tid * 16 + j;
            size_t base = (size_t)(bk >> 11) * NN + lidx[bk];
            int len = clens[base];
            len = len < 0 ? 0 : (len > CC ? CC : len);
            myl[j] = len; msum += len;
        }
        ls[tid] = msum;
        __syncthreads();
        for (int d = 1; d < 256; d <<= 1) {
            int v = (tid >= d) ? ls[tid - d] : 0;
            __syncthreads();
            ls[tid] += v;
            __syncthreads();
        }
        int run = ls[tid] - msum;   // exclusive prefix
#pragma unroll
        for (int j = 0; j < 16; ++j) { off[tid * 16 + j] = run; run += myl[j]; }
        if (tid == 255) off[4096] = run;
        return;
    }
    if (bid >= 336) {    // span gather
        const int bk = bid - 336;
        const float* src = span + ((size_t)(bk >> 11) * NN + lidx[bk]) * DSP;
        float4 x = *(const float4*)(src + tid * 8);
        float4 y = *(const float4*)(src + tid * 8 + 4);
        pack8(&A16[(size_t)bk * DSP + tid * 8], x, y);
        return;
    }
    if (bid < 256) {     // W1 span-part transpose
        __shared__ float t[64][65];
        const int k0 = (bid >> 3) * 64, n0 = (bid & 7) * 64;
#pragma unroll
        for (int p = 0; p < 16; ++p) {
            int flat = p * 256 + tid;
            int r = flat >> 6, c = flat & 63;
            t[r][c] = W1[(size_t)(k0 + r) * HD + n0 + c];
        }
        __syncthreads();
#pragma unroll
        for (int p = 0; p < 16; ++p) {
            int flat = p * 256 + tid;
            int c = flat >> 6, r = flat & 63;
            W1sT[(size_t)(n0 + c) * DSP + k0 + r] = f2bf(t[r][c]);
        }
    } else {             // entity-weight fragments
        int t0 = (bid - 256) * 256 + tid;   // 0..20479
        int lane = t0 & 63;
        int ks = (t0 >> 6) % 10;
        int ncg = (t0 >> 6) / 10;
        int col = ncg * 16 + (lane & 15);
        int kb = ks * 32 + ((lane >> 4) << 3);
        unsigned short v[8];
#pragma unroll
        for (int j = 0; j < 8; ++j) {
            int k = kb + j;
            v[j] = (k < ED) ? f2bf(W1[(size_t)(DSP + k) * HD + col]) : (unsigned short)0;
        }
        *(short8*)&w1ef[(size_t)t0 * 8] = *(short8*)v;
    }
}

// ---------------------------------------------------------------------------
// Kernel 2: span GEMM (bid < 512) + compaction fill (bid >= 512).
// 4-deep LDS pipeline, counted vmcnt. (unchanged R9)
// ---------------------------------------------------------------------------
__global__ __launch_bounds__(256) void gemm_and_fill(
    const unsigned short* __restrict__ A16,   // [4096][2048] bf16
    const unsigned short* __restrict__ BT,    // [512][2048]  bf16
    const float* __restrict__ b1,
    unsigned short* __restrict__ Cout,        // [4096][512] bf16 (+b1)
    const int* __restrict__ lidx,
    const int* __restrict__ cands,
    const int* __restrict__ clens,
    const int* __restrict__ off,
    int* __restrict__ compact_cand,
    int* __restrict__ compact_meta)
{
    const int tid = threadIdx.x;

    if (blockIdx.x >= 512) {     // ---- fill path ----
        int fb = blockIdx.x - 512;
        int item0 = (fb * 256 + tid) * 4;
#pragma unroll
        for (int q = 0; q < 4; ++q) {
            int item = item0 + q;
            int bk = item >> 4, c = item & 15;
            size_t base = (size_t)(bk >> 11) * NN + lidx[bk];
            int len = clens[base];
            len = len > CC ? CC : len;
            if (c < len) {
                int pos = off[bk] + c;
                compact_cand[pos] = cands[base * CC + c];
                compact_meta[pos] = item;   // (bk<<4)|c
            }
        }
        return;
    }

    // ---- GEMM path ----
    __shared__ __align__(16) unsigned short As[4][64 * 64];   // 32 KB
    __shared__ __align__(16) unsigned short Bs[4][64 * 64];   // 32 KB
    const int l = tid & 63, wid = tid >> 6;
    const int wr = (wid >> 1) * 32, wc = (wid & 1) * 32;

    const int bid = blockIdx.x;
    const int brow = ((bid & 7) * 8 + ((bid >> 3) >> 3)) * 64;
    const int bcol = (((bid >> 3) & 7)) * 64;

    const int s0 = tid, s1 = tid + 256;
    const int r0 = s0 >> 3, c0 = ((s0 & 7) ^ (r0 & 7)) * 8;
    const int r1 = s1 >> 3, c1 = ((s1 & 7) ^ (r1 & 7)) * 8;
    const unsigned short* ga0 = A16 + (size_t)(brow + r0) * DSP + c0;
    const unsigned short* ga1 = A16 + (size_t)(brow + r1) * DSP + c1;
    const unsigned short* gb0 = BT + (size_t)(bcol + r0) * DSP + c0;
    const unsigned short* gb1 = BT + (size_t)(bcol + r1) * DSP + c1;

    int offA[2][2], offB[2][2];
#pragma unroll
    for (int mf = 0; mf < 2; ++mf) {
        int row = wr + mf * 16 + (l & 15);
#pragma unroll
        for (int kk = 0; kk < 2; ++kk)
            offA[mf][kk] = row * 64 + (((kk * 4) + (l >> 4)) ^ (row & 7)) * 8;
    }
#pragma unroll
    for (int nf = 0; nf < 2; ++nf) {
        int row = wc + nf * 16 + (l & 15);
#pragma unroll
        for (int kk = 0; kk < 2; ++kk)
            offB[nf][kk] = row * 64 + (((kk * 4) + (l >> 4)) ^ (row & 7)) * 8;
    }

    f32x4 z = {0.f, 0.f, 0.f, 0.f};
    f32x4 acc[2][2] = {{z, z}, {z, z}};

    auto stage = [&](int buf, int t) {
        const int k0 = t * 64;
        gl_lds16(ga0 + k0, &As[buf][s0 * 8]);
        gl_lds16(ga1 + k0, &As[buf][s1 * 8]);
        gl_lds16(gb0 + k0, &Bs[buf][s0 * 8]);
        gl_lds16(gb1 + k0, &Bs[buf][s1 * 8]);
    };

    auto compute = [&](int buf) {
        short8 am[2][2], bn[2][2];
#pragma unroll
        for (int mf = 0; mf < 2; ++mf)
#pragma unroll
            for (int kk = 0; kk < 2; ++kk)
                am[mf][kk] = *(const short8*)&As[buf][offA[mf][kk]];
#pragma unroll
        for (int nf = 0; nf < 2; ++nf)
#pragma unroll
            for (int kk = 0; kk < 2; ++kk)
                bn[nf][kk] = *(const short8*)&Bs[buf][offB[nf][kk]];
#pragma unroll
        for (int m = 0; m < 2; ++m)
#pragma unroll
            for (int n = 0; n < 2; ++n)
#pragma unroll
                for (int kk = 0; kk < 2; ++kk)
                    acc[m][n] = MFMA16(am[m][kk], bn[n][kk], acc[m][n]);
    };

    stage(0, 0);
    stage(1, 1);
    stage(2, 2);

    for (int t = 0; t < 29; ++t) {
        asm volatile("s_waitcnt vmcnt(8)" ::: "memory");
        __builtin_amdgcn_s_barrier();
        stage((t + 3) & 3, t + 3);
        compute(t & 3);
    }
    asm volatile("s_waitcnt vmcnt(8)" ::: "memory");
    __builtin_amdgcn_s_barrier();
    compute(29 & 3);
    asm volatile("s_waitcnt vmcnt(4)" ::: "memory");
    __builtin_amdgcn_s_barrier();
    compute(30 & 3);
    asm volatile("s_waitcnt vmcnt(0)" ::: "memory");
    __builtin_amdgcn_s_barrier();
    compute(31 & 3);

#pragma unroll
    for (int n = 0; n < 2; ++n) {
        int col = bcol + wc + n * 16 + (l & 15);
        float b1v = b1[col];
#pragma unroll
        for (int m = 0; m < 2; ++m) {
            int row0 = brow + wr + m * 16 + (l >> 4) * 4;
#pragma unroll
            for (int r = 0; r < 4; ++r)
                Cout[(size_t)(row0 + r) * HD + col] = f2bf(acc[m][n][r] + b1v);
        }
    }
}

// ---------------------------------------------------------------------------
// Kernel 3: compacted entity MFMA + fused ReLU/W2/BCE + LAST-BLOCK reduce.
// CHANGE (R11): 256-thread / 4-wave / 64-slot blocks; wave w owns h-cols
// [w*128, w*128+128) (nc=8) -> 32 MFMA/wave/step (R4 density) with ~2
// working blocks/CU (barrier overlap). 2-stage staging (R9). Final sum
// fused via threadfence+ticket: last block sums bpart[0..1023] in fixed
// order -> deterministic output, no 4th kernel.
// ---------------------------------------------------------------------------
__global__ __launch_bounds__(256) void ent_mfma(
    const unsigned short* __restrict__ w1ef,
    const unsigned short* __restrict__ span_part,  // [4096][512] bf16 (+b1)
    const float* __restrict__ emb,        // [V][300] f32
    const float* __restrict__ W2,         // [512]
    const float* __restrict__ b2,         // [1]
    const int*   __restrict__ lidx,       // [B*K]
    const float* __restrict__ targets,    // [B*N*16]
    const int*   __restrict__ compact_cand,
    const int*   __restrict__ compact_meta,
    const int*   __restrict__ off,        // off[4096] = total
    float*       __restrict__ blockPartial, // [1024]
    unsigned*    __restrict__ ticket,
    float*       __restrict__ out)
{
    const int total = off[4096];
    const int bid = blockIdx.x;
    const int slotBase = bid * 64;
    const int tid = threadIdx.x;
    const int wid = tid >> 6, l = tid & 63;

    __shared__ __align__(16) unsigned short As[2][4 * 64 * 8];  // 8 KB
    __shared__ float shp[4][16][4];                             // 1 KB
    __shared__ int   meta_s[64];
    __shared__ unsigned tk;

    float bsum = 0.f;

    if (slotBase < total) {   // block-uniform branch
        if (tid < 64) {
            int slot = slotBase + tid;
            meta_s[tid] = (slot < total) ? compact_meta[slot] : -1;
        }

        // staging identity: tile g = wid, slot = g*16 + (l&15), kb = (l>>4)*8
        const int slot_s = slotBase + wid * 16 + (l & 15);
        const int cid = (slot_s < total) ? compact_cand[slot_s] : 0;
        const float* erow = emb + (size_t)cid * ED;
        const int kb = (l >> 4) * 8;

        // prologue: ks=0
        float4 lx = *(const float4*)(erow + kb);
        float4 ly = *(const float4*)(erow + kb + 4);
        pack8(&As[0][tid * 8], lx, ly);
        __syncthreads();

        f32x4 z = {0.f, 0.f, 0.f, 0.f};
        f32x4 acc[4][8];
#pragma unroll
        for (int g = 0; g < 4; ++g)
#pragma unroll
            for (int nc = 0; nc < 8; ++nc) acc[g][nc] = z;

        int cur = 0;
        for (int ks = 0; ks < 10; ++ks) {
            const bool pf = (ks < 9);
            if (pf) {   // issue-early
                int k = (ks + 1) * 32 + kb;
                if (k + 8 <= ED) {
                    lx = *(const float4*)(erow + k);
                    ly = *(const float4*)(erow + k + 4);
                } else {
                    float tmp[8];
#pragma unroll
                    for (int j = 0; j < 8; ++j) tmp[j] = (k + j < ED) ? erow[k + j] : 0.f;
                    lx = make_float4(tmp[0], tmp[1], tmp[2], tmp[3]);
                    ly = make_float4(tmp[4], tmp[5], tmp[6], tmp[7]);
                }
            }
            short8 af[4];
#pragma unroll
            for (int g = 0; g < 4; ++g)
                af[g] = *(const short8*)&As[cur][(g * 64 + l) * 8];
#pragma unroll
            for (int nc = 0; nc < 8; ++nc) {
                short8 bf = *(const short8*)&w1ef[(((size_t)(wid * 8 + nc) * 10 + ks) * 64 + l) * 8];
#pragma unroll
                for (int g = 0; g < 4; ++g)
                    acc[g][nc] = MFMA16(af[g], bf, acc[g][nc]);
            }
            if (pf) {   // write-late
                pack8(&As[cur ^ 1][tid * 8], lx, ly);
            }
            __syncthreads();
            cur ^= 1;
        }

        // epilogue: relu(acc + span_h[bk(slot)]) . W2, 16-lane reduce
        float w2v[8];
#pragma unroll
        for (int nc = 0; nc < 8; ++nc) w2v[nc] = W2[wid * 128 + nc * 16 + (l & 15)];
        const int rq = (l >> 4) * 4;

#pragma unroll
        for (int g = 0; g < 4; ++g) {
            int bkR[4];
#pragma unroll
            for (int i = 0; i < 4; ++i) {
                int m = meta_s[g * 16 + rq + i];
                bkR[i] = (m >= 0) ? (m >> 4) : 0;
            }
            float s[4] = {0.f, 0.f, 0.f, 0.f};
#pragma unroll
            for (int nc = 0; nc < 8; ++nc) {
                int col = wid * 128 + nc * 16 + (l & 15);
                f32x4 a = acc[g][nc];
#pragma unroll
                for (int i = 0; i < 4; ++i) {
                    float sp = bf2f(span_part[(size_t)bkR[i] * HD + col]);
                    s[i] += fmaxf(a[i] + sp, 0.f) * w2v[nc];
                }
            }
#pragma unroll
            for (int m = 1; m < 16; m <<= 1) {
#pragma unroll
                for (int i = 0; i < 4; ++i) s[i] += __shfl_xor(s[i], m, 64);
            }
            if ((l & 15) == 0) {
#pragma unroll
                for (int i = 0; i < 4; ++i) shp[g][rq + i][wid] = s[i];
            }
        }
        __syncthreads();

        // fused BCE: wave 0, one compacted slot per lane
        if (wid == 0) {
            float val = 0.f;
            int m = meta_s[l];
            if (m >= 0) {
                int bk = m >> 4, c = m & 15;
                size_t base = (size_t)(bk >> 11) * NN + lidx[bk];
                const float* p = &shp[l >> 4][l & 15][0];
                float sc = (p[0] + p[1]) + (p[2] + p[3]) + b2[0];
                float tg = targets[base * CC + c];
                val = fmaxf(sc, 0.f) + log1pf(expf(-fabsf(sc))) - sc * tg;
            }
#pragma unroll
            for (int m2 = 32; m2; m2 >>= 1) val += __shfl_xor(val, m2, 64);
            bsum = val;   // lane 0 holds block sum
        }
    }

    // ---- publish partial + ticket; last block does fixed-order final sum ----
    if (tid == 0) {
        blockPartial[bid] = bsum;
        __threadfence();
        tk = atomicAdd(ticket, 1u);
    }
    __syncthreads();
    if (tk == gridDim.x - 1) {    // last block (any one; sum order is fixed)
        __threadfence();
        volatile const float* vb = blockPartial;
        float s = (vb[tid] + vb[tid + 256]) + (vb[tid + 512] + vb[tid + 768]);
        __shared__ float red[4];
#pragma unroll
        for (int m = 32; m; m >>= 1) s += __shfl_xor(s, m, 64);
        if ((tid & 63) == 0) red[tid >> 6] = s;
        __syncthreads();
        if (tid == 0) out[0] = (red[0] + red[1]) + (red[2] + red[3]);  // WEIGHT=1
    }
}

// ---------------------------------------------------------------------------
extern "C" void kernel_launch(void* const* d_in, const int* in_sizes, int n_in,
                              void* d_out, int out_size, void* d_ws, size_t ws_size,
                              hipStream_t stream) {
    const float* span    = (const float*)d_in[0];
    const float* targets = (const float*)d_in[1];
    const float* emb     = (const float*)d_in[2];
    const float* W1      = (const float*)d_in[3];
    const float* b1      = (const float*)d_in[4];
    const float* W2      = (const float*)d_in[5];
    const float* b2      = (const float*)d_in[6];
    const int*   lidx    = (const int*)d_in[7];
    const int*   cands   = (const int*)d_in[8];
    const int*   clens   = (const int*)d_in[9];

    char* ws = (char*)d_ws;
    unsigned short* W1sT      = (unsigned short*)(ws);             // 2 MB
    unsigned short* w1ef      = (unsigned short*)(ws + 2097152);   // 320 KB
    unsigned short* A16       = (unsigned short*)(ws + 2424832);   // 16 MB
    unsigned short* span_part = (unsigned short*)(ws + 19202048);  // 4 MB bf16
    int*            off       = (int*)(ws + 23396352);             // 16.4 KB
    int*            ccand     = (int*)(ws + 23412740);             // 256 KB
    int*            cmeta     = (int*)(ws + 23674884);             // 256 KB
    float*          bpart     = (float*)(ws + 23937028);           // 4 KB
    unsigned*       ticket    = (unsigned*)(ws + 23941124);        // 4 B

    prep_gather_scan<<<4433, 256, 0, stream>>>(W1, span, lidx, clens,
                                               W1sT, w1ef, A16, off, ticket);
    gemm_and_fill<<<576, 256, 0, stream>>>(A16, W1sT, b1, span_part,
                                           lidx, cands, clens, off, ccand, cmeta);
    ent_mfma<<<1024, 256, 0, stream>>>(w1ef, span_part, emb, W2, b2,
                                       lidx, targets, ccand, cmeta, off,
                                       bpart, ticket, (float*)d_out);
}

// Round 12
// 71.275 us; speedup vs baseline: 1.3613x; 1.3613x over previous
//
#include <hip/hip_runtime.h>
#include <math.h>

#define NN 4096
#define CC 16
#define DSP 2048
#define ED 300
#define HD 512

typedef __attribute__((ext_vector_type(8))) short short8;
typedef __attribute__((ext_vector_type(4))) float f32x4;

#define MFMA16(a, b, c) __builtin_amdgcn_mfma_f32_16x16x32_bf16((a), (b), (c), 0, 0, 0)

__device__ __forceinline__ unsigned short f2bf(float x) {
    unsigned u = __builtin_bit_cast(unsigned, x);
    u += 0x7FFFu + ((u >> 16) & 1u);   // RNE
    return (unsigned short)(u >> 16);
}

__device__ __forceinline__ float bf2f(unsigned short u) {
    return __builtin_bit_cast(float, (unsigned)u << 16);
}

__device__ __forceinline__ void gl_lds16(const void* g, void* l) {
    __builtin_amdgcn_global_load_lds(
        (const __attribute__((address_space(1))) unsigned*)g,
        (__attribute__((address_space(3))) unsigned*)l, 16, 0, 0);
}

__device__ __forceinline__ void pack8(unsigned short* dst, float4 a, float4 b) {
    unsigned short v[8] = { f2bf(a.x), f2bf(a.y), f2bf(a.z), f2bf(a.w),
                            f2bf(b.x), f2bf(b.y), f2bf(b.z), f2bf(b.w) };
    *(short8*)dst = *(short8*)v;
}

// ---------------------------------------------------------------------------
// Kernel 1: weight prep + span gather + length prefix-scan (+ticket zero).
// (R9 structure; ticket zeroing added at the scan block)
// ---------------------------------------------------------------------------
__global__ __launch_bounds__(256) void prep_gather_scan(
    const float* __restrict__ W1,
    const float* __restrict__ span,
    const int*   __restrict__ lidx,
    const int*   __restrict__ clens,
    unsigned short* __restrict__ W1sT,
    unsigned short* __restrict__ w1ef,
    unsigned short* __restrict__ A16,
    int*            __restrict__ off,      // [4097], off[4096] = total
    unsigned*       __restrict__ ticket)
{
    const int bid = blockIdx.x, tid = threadIdx.x;

    if (bid == 4432) {   // scan block
        if (tid == 0) *ticket = 0u;        // re-zero every call (graph replay)
        __shared__ int ls[256];
        int myl[16];
        int msum = 0;
#pragma unroll
        for (int j = 0; j < 16; ++j) {
            int bk = tid * 16 + j;
            size_t base = (size_t)(bk >> 11) * NN + lidx[bk];
            int len = clens[base];
            len = len < 0 ? 0 : (len > CC ? CC : len);
            myl[j] = len; msum += len;
        }
        ls[tid] = msum;
        __syncthreads();
        for (int d = 1; d < 256; d <<= 1) {
            int v = (tid >= d) ? ls[tid - d] : 0;
            __syncthreads();
            ls[tid] += v;
            __syncthreads();
        }
        int run = ls[tid] - msum;   // exclusive prefix
#pragma unroll
        for (int j = 0; j < 16; ++j) { off[tid * 16 + j] = run; run += myl[j]; }
        if (tid == 255) off[4096] = run;
        return;
    }
    if (bid >= 336) {    // span gather
        const int bk = bid - 336;
        const float* src = span + ((size_t)(bk >> 11) * NN + lidx[bk]) * DSP;
        float4 x = *(const float4*)(src + tid * 8);
        float4 y = *(const float4*)(src + tid * 8 + 4);
        pack8(&A16[(size_t)bk * DSP + tid * 8], x, y);
        return;
    }
    if (bid < 256) {     // W1 span-part transpose
        __shared__ float t[64][65];
        const int k0 = (bid >> 3) * 64, n0 = (bid & 7) * 64;
#pragma unroll
        for (int p = 0; p < 16; ++p) {
            int flat = p * 256 + tid;
            int r = flat >> 6, c = flat & 63;
            t[r][c] = W1[(size_t)(k0 + r) * HD + n0 + c];
        }
        __syncthreads();
#pragma unroll
        for (int p = 0; p < 16; ++p) {
            int flat = p * 256 + tid;
            int c = flat >> 6, r = flat & 63;
            W1sT[(size_t)(n0 + c) * DSP + k0 + r] = f2bf(t[r][c]);
        }
    } else {             // entity-weight fragments
        int t0 = (bid - 256) * 256 + tid;   // 0..20479
        int lane = t0 & 63;
        int ks = (t0 >> 6) % 10;
        int ncg = (t0 >> 6) / 10;
        int col = ncg * 16 + (lane & 15);
        int kb = ks * 32 + ((lane >> 4) << 3);
        unsigned short v[8];
#pragma unroll
        for (int j = 0; j < 8; ++j) {
            int k = kb + j;
            v[j] = (k < ED) ? f2bf(W1[(size_t)(DSP + k) * HD + col]) : (unsigned short)0;
        }
        *(short8*)&w1ef[(size_t)t0 * 8] = *(short8*)v;
    }
}

// ---------------------------------------------------------------------------
// Kernel 2: span GEMM (bid < 512) + compaction fill (bid >= 512).
// 4-deep LDS pipeline, counted vmcnt. (unchanged R9)
// ---------------------------------------------------------------------------
__global__ __launch_bounds__(256) void gemm_and_fill(
    const unsigned short* __restrict__ A16,   // [4096][2048] bf16
    const unsigned short* __restrict__ BT,    // [512][2048]  bf16
    const float* __restrict__ b1,
    unsigned short* __restrict__ Cout,        // [4096][512] bf16 (+b1)
    const int* __restrict__ lidx,
    const int* __restrict__ cands,
    const int* __restrict__ clens,
    const int* __restrict__ off,
    int* __restrict__ compact_cand,
    int* __restrict__ compact_meta)
{
    const int tid = threadIdx.x;

    if (blockIdx.x >= 512) {     // ---- fill path ----
        int fb = blockIdx.x - 512;
        int item0 = (fb * 256 + tid) * 4;
#pragma unroll
        for (int q = 0; q < 4; ++q) {
            int item = item0 + q;
            int bk = item >> 4, c = item & 15;
            size_t base = (size_t)(bk >> 11) * NN + lidx[bk];
            int len = clens[base];
            len = len > CC ? CC : len;
            if (c < len) {
                int pos = off[bk] + c;
                compact_cand[pos] = cands[base * CC + c];
                compact_meta[pos] = item;   // (bk<<4)|c
            }
        }
        return;
    }

    // ---- GEMM path ----
    __shared__ __align__(16) unsigned short As[4][64 * 64];   // 32 KB
    __shared__ __align__(16) unsigned short Bs[4][64 * 64];   // 32 KB
    const int l = tid & 63, wid = tid >> 6;
    const int wr = (wid >> 1) * 32, wc = (wid & 1) * 32;

    const int bid = blockIdx.x;
    const int brow = ((bid & 7) * 8 + ((bid >> 3) >> 3)) * 64;
    const int bcol = (((bid >> 3) & 7)) * 64;

    const int s0 = tid, s1 = tid + 256;
    const int r0 = s0 >> 3, c0 = ((s0 & 7) ^ (r0 & 7)) * 8;
    const int r1 = s1 >> 3, c1 = ((s1 & 7) ^ (r1 & 7)) * 8;
    const unsigned short* ga0 = A16 + (size_t)(brow + r0) * DSP + c0;
    const unsigned short* ga1 = A16 + (size_t)(brow + r1) * DSP + c1;
    const unsigned short* gb0 = BT + (size_t)(bcol + r0) * DSP + c0;
    const unsigned short* gb1 = BT + (size_t)(bcol + r1) * DSP + c1;

    int offA[2][2], offB[2][2];
#pragma unroll
    for (int mf = 0; mf < 2; ++mf) {
        int row = wr + mf * 16 + (l & 15);
#pragma unroll
        for (int kk = 0; kk < 2; ++kk)
            offA[mf][kk] = row * 64 + (((kk * 4) + (l >> 4)) ^ (row & 7)) * 8;
    }
#pragma unroll
    for (int nf = 0; nf < 2; ++nf) {
        int row = wc + nf * 16 + (l & 15);
#pragma unroll
        for (int kk = 0; kk < 2; ++kk)
            offB[nf][kk] = row * 64 + (((kk * 4) + (l >> 4)) ^ (row & 7)) * 8;
    }

    f32x4 z = {0.f, 0.f, 0.f, 0.f};
    f32x4 acc[2][2] = {{z, z}, {z, z}};

    auto stage = [&](int buf, int t) {
        const int k0 = t * 64;
        gl_lds16(ga0 + k0, &As[buf][s0 * 8]);
        gl_lds16(ga1 + k0, &As[buf][s1 * 8]);
        gl_lds16(gb0 + k0, &Bs[buf][s0 * 8]);
        gl_lds16(gb1 + k0, &Bs[buf][s1 * 8]);
    };

    auto compute = [&](int buf) {
        short8 am[2][2], bn[2][2];
#pragma unroll
        for (int mf = 0; mf < 2; ++mf)
#pragma unroll
            for (int kk = 0; kk < 2; ++kk)
                am[mf][kk] = *(const short8*)&As[buf][offA[mf][kk]];
#pragma unroll
        for (int nf = 0; nf < 2; ++nf)
#pragma unroll
            for (int kk = 0; kk < 2; ++kk)
                bn[nf][kk] = *(const short8*)&Bs[buf][offB[nf][kk]];
#pragma unroll
        for (int m = 0; m < 2; ++m)
#pragma unroll
            for (int n = 0; n < 2; ++n)
#pragma unroll
                for (int kk = 0; kk < 2; ++kk)
                    acc[m][n] = MFMA16(am[m][kk], bn[n][kk], acc[m][n]);
    };

    stage(0, 0);
    stage(1, 1);
    stage(2, 2);

    for (int t = 0; t < 29; ++t) {
        asm volatile("s_waitcnt vmcnt(8)" ::: "memory");
        __builtin_amdgcn_s_barrier();
        stage((t + 3) & 3, t + 3);
        compute(t & 3);
    }
    asm volatile("s_waitcnt vmcnt(8)" ::: "memory");
    __builtin_amdgcn_s_barrier();
    compute(29 & 3);
    asm volatile("s_waitcnt vmcnt(4)" ::: "memory");
    __builtin_amdgcn_s_barrier();
    compute(30 & 3);
    asm volatile("s_waitcnt vmcnt(0)" ::: "memory");
    __builtin_amdgcn_s_barrier();
    compute(31 & 3);

#pragma unroll
    for (int n = 0; n < 2; ++n) {
        int col = bcol + wc + n * 16 + (l & 15);
        float b1v = b1[col];
#pragma unroll
        for (int m = 0; m < 2; ++m) {
            int row0 = brow + wr + m * 16 + (l >> 4) * 4;
#pragma unroll
            for (int r = 0; r < 4; ++r)
                Cout[(size_t)(row0 + r) * HD + col] = f2bf(acc[m][n][r] + b1v);
        }
    }
}

// ---------------------------------------------------------------------------
// Kernel 3: compacted entity MFMA + fused ReLU/W2/BCE. EXACT R9 structure
// (8 waves, 128 slots/block, acc[8][4], 2-stage staging). Single change:
// final reduce fused via threadfence+ticket — last arriving block sums the
// 512 partials in fixed order (bit-deterministic), removing kernel 4.
// ---------------------------------------------------------------------------
__global__ __launch_bounds__(512) void ent_mfma(
    const unsigned short* __restrict__ w1ef,
    const unsigned short* __restrict__ span_part,  // [4096][512] bf16 (+b1)
    const float* __restrict__ emb,        // [V][300] f32
    const float* __restrict__ W2,         // [512]
    const float* __restrict__ b2,         // [1]
    const int*   __restrict__ lidx,       // [B*K]
    const float* __restrict__ targets,    // [B*N*16]
    const int*   __restrict__ compact_cand,
    const int*   __restrict__ compact_meta,
    const int*   __restrict__ off,        // off[4096] = total
    float*       __restrict__ blockPartial, // [512]
    unsigned*    __restrict__ ticket,
    float*       __restrict__ out)
{
    const int total = off[4096];
    const int bid = blockIdx.x;
    const int slotBase = bid * 128;
    const int tid = threadIdx.x;
    const int wid = tid >> 6, l = tid & 63;

    __shared__ __align__(16) unsigned short As[2][8 * 64 * 8];  // 16 KB
    __shared__ float shp[8][16][8];                             // 4 KB
    __shared__ int   meta_s[128];
    __shared__ float wred[8];
    __shared__ unsigned tk;

    float bsum = 0.f;

    if (slotBase < total) {   // block-uniform branch
        if (tid < 128) {
            int slot = slotBase + tid;
            meta_s[tid] = (slot < total) ? compact_meta[slot] : -1;
        }

        // staging identity: slot-in-tile = l&15, k-chunk = (l>>4)*8, tile=wid
        const int slot_s = slotBase + wid * 16 + (l & 15);
        const int cid = (slot_s < total) ? compact_cand[slot_s] : 0;
        const float* erow = emb + (size_t)cid * ED;
        const int kb = (l >> 4) * 8;
        const int ht = wid;

        // prologue: ks=0
        float4 lx = *(const float4*)(erow + kb);
        float4 ly = *(const float4*)(erow + kb + 4);
        pack8(&As[0][tid * 8], lx, ly);
        __syncthreads();

        f32x4 z = {0.f, 0.f, 0.f, 0.f};
        f32x4 acc[8][4];
#pragma unroll
        for (int g = 0; g < 8; ++g)
#pragma unroll
            for (int nc = 0; nc < 4; ++nc) acc[g][nc] = z;

        int cur = 0;
        for (int ks = 0; ks < 10; ++ks) {
            const bool pf = (ks < 9);
            if (pf) {   // T14 issue-early
                int k = (ks + 1) * 32 + kb;
                if (k + 8 <= ED) {
                    lx = *(const float4*)(erow + k);
                    ly = *(const float4*)(erow + k + 4);
                } else {
                    float tmp[8];
#pragma unroll
                    for (int j = 0; j < 8; ++j) tmp[j] = (k + j < ED) ? erow[k + j] : 0.f;
                    lx = make_float4(tmp[0], tmp[1], tmp[2], tmp[3]);
                    ly = make_float4(tmp[4], tmp[5], tmp[6], tmp[7]);
                }
            }
            short8 af[8];
#pragma unroll
            for (int g = 0; g < 8; ++g)
                af[g] = *(const short8*)&As[cur][(g * 64 + l) * 8];
#pragma unroll
            for (int nc = 0; nc < 4; ++nc) {
                short8 bf = *(const short8*)&w1ef[(((size_t)(ht * 4 + nc) * 10 + ks) * 64 + l) * 8];
#pragma unroll
                for (int g = 0; g < 8; ++g)
                    acc[g][nc] = MFMA16(af[g], bf, acc[g][nc]);
            }
            if (pf) {   // write-late
                pack8(&As[cur ^ 1][tid * 8], lx, ly);
            }
            __syncthreads();
            cur ^= 1;
        }

        // epilogue: relu(acc + span_h[bk(slot)]) . W2, 16-lane reduce
        float w2v[4];
#pragma unroll
        for (int nc = 0; nc < 4; ++nc) w2v[nc] = W2[ht * 64 + nc * 16 + (l & 15)];
        const int rq = (l >> 4) * 4;

#pragma unroll
        for (int g = 0; g < 8; ++g) {
            int bkR[4];
#pragma unroll
            for (int i = 0; i < 4; ++i) {
                int m = meta_s[g * 16 + rq + i];
                bkR[i] = (m >= 0) ? (m >> 4) : 0;
            }
            float s[4] = {0.f, 0.f, 0.f, 0.f};
#pragma unroll
            for (int nc = 0; nc < 4; ++nc) {
                int col = ht * 64 + nc * 16 + (l & 15);
                f32x4 a = acc[g][nc];
#pragma unroll
                for (int i = 0; i < 4; ++i) {
                    float sp = bf2f(span_part[(size_t)bkR[i] * HD + col]);
                    s[i] += fmaxf(a[i] + sp, 0.f) * w2v[nc];
                }
            }
#pragma unroll
            for (int m = 1; m < 16; m <<= 1) {
#pragma unroll
                for (int i = 0; i < 4; ++i) s[i] += __shfl_xor(s[i], m, 64);
            }
            if ((l & 15) == 0) {
#pragma unroll
                for (int i = 0; i < 4; ++i) shp[g][rq + i][ht] = s[i];
            }
        }
        __syncthreads();

        // fused BCE: 128 threads own one compacted slot each
        float val = 0.f;
        if (tid < 128) {
            int m = meta_s[tid];
            if (m >= 0) {
                int bk = m >> 4, c = m & 15;
                size_t base = (size_t)(bk >> 11) * NN + lidx[bk];
                const float* p = &shp[tid >> 4][tid & 15][0];
                float sc = ((p[0] + p[1]) + (p[2] + p[3])) +
                           ((p[4] + p[5]) + (p[6] + p[7])) + b2[0];
                float tg = targets[base * CC + c];
                val = fmaxf(sc, 0.f) + log1pf(expf(-fabsf(sc))) - sc * tg;
            }
        }
#pragma unroll
        for (int m = 32; m; m >>= 1) val += __shfl_xor(val, m, 64);
        if (l == 0) wred[wid] = val;
        __syncthreads();
        if (tid == 0) {
            float s = 0.f;
#pragma unroll
            for (int w = 0; w < 8; ++w) s += wred[w];
            bsum = s;
        }
    }

    // ---- publish partial + ticket; last block does fixed-order final sum ----
    if (tid == 0) {
        blockPartial[bid] = bsum;
        __threadfence();
        tk = atomicAdd(ticket, 1u);
    }
    __syncthreads();
    if (tk == gridDim.x - 1) {    // exactly one block; sum order is fixed
        __threadfence();
        if (tid < 256) {
            volatile const float* vb = blockPartial;
            float s = vb[tid] + vb[tid + 256];
            __shared__ float red[4];
#pragma unroll
            for (int m = 32; m; m >>= 1) s += __shfl_xor(s, m, 64);
            if ((tid & 63) == 0) red[tid >> 6] = s;
            __syncthreads();
            if (tid == 0) out[0] = (red[0] + red[1]) + (red[2] + red[3]); // WEIGHT=1
        }
    }
}

// ---------------------------------------------------------------------------
extern "C" void kernel_launch(void* const* d_in, const int* in_sizes, int n_in,
                              void* d_out, int out_size, void* d_ws, size_t ws_size,
                              hipStream_t stream) {
    const float* span    = (const float*)d_in[0];
    const float* targets = (const float*)d_in[1];
    const float* emb     = (const float*)d_in[2];
    const float* W1      = (const float*)d_in[3];
    const float* b1      = (const float*)d_in[4];
    const float* W2      = (const float*)d_in[5];
    const float* b2      = (const float*)d_in[6];
    const int*   lidx    = (const int*)d_in[7];
    const int*   cands   = (const int*)d_in[8];
    const int*   clens   = (const int*)d_in[9];

    char* ws = (char*)d_ws;
    unsigned short* W1sT      = (unsigned short*)(ws);             // 2 MB
    unsigned short* w1ef      = (unsigned short*)(ws + 2097152);   // 320 KB
    unsigned short* A16       = (unsigned short*)(ws + 2424832);   // 16 MB
    unsigned short* span_part = (unsigned short*)(ws + 19202048);  // 4 MB bf16
    int*            off       = (int*)(ws + 23396352);             // 16.4 KB
    int*            ccand     = (int*)(ws + 23412740);             // 256 KB
    int*            cmeta     = (int*)(ws + 23674884);             // 256 KB
    float*          bpart     = (float*)(ws + 23937028);           // 2 KB
    unsigned*       ticket    = (unsigned*)(ws + 23939076);        // 4 B

    prep_gather_scan<<<4433, 256, 0, stream>>>(W1, span, lidx, clens,
                                               W1sT, w1ef, A16, off, ticket);
    gemm_and_fill<<<576, 256, 0, stream>>>(A16, W1sT, b1, span_part,
                                           lidx, cands, clens, off, ccand, cmeta);
    ent_mfma<<<512, 512, 0, stream>>>(w1ef, span_part, emb, W2, b2,
                                      lidx, targets, ccand, cmeta, off,
                                      bpart, ticket, (float*)d_out);
}

// Round 13
// 62.571 us; speedup vs baseline: 1.5507x; 1.1391x over previous
//
#include <hip/hip_runtime.h>
#include <math.h>

#define NN 4096
#define CC 16
#define DSP 2048
#define ED 300
#define HD 512

typedef __attribute__((ext_vector_type(8))) short short8;
typedef __attribute__((ext_vector_type(4))) float f32x4;

#define MFMA16(a, b, c) __builtin_amdgcn_mfma_f32_16x16x32_bf16((a), (b), (c), 0, 0, 0)

__device__ __forceinline__ unsigned short f2bf(float x) {
    unsigned u = __builtin_bit_cast(unsigned, x);
    u += 0x7FFFu + ((u >> 16) & 1u);   // RNE
    return (unsigned short)(u >> 16);
}

__device__ __forceinline__ float bf2f(unsigned short u) {
    return __builtin_bit_cast(float, (unsigned)u << 16);
}

__device__ __forceinline__ void gl_lds16(const void* g, void* l) {
    __builtin_amdgcn_global_load_lds(
        (const __attribute__((address_space(1))) unsigned*)g,
        (__attribute__((address_space(3))) unsigned*)l, 16, 0, 0);
}

__device__ __forceinline__ void pack8(unsigned short* dst, float4 a, float4 b) {
    unsigned short v[8] = { f2bf(a.x), f2bf(a.y), f2bf(a.z), f2bf(a.w),
                            f2bf(b.x), f2bf(b.y), f2bf(b.z), f2bf(b.w) };
    *(short8*)dst = *(short8*)v;
}

// ---------------------------------------------------------------------------
// Kernel 1: weight prep + span gather + length prefix-scan. (exact R9)
// ---------------------------------------------------------------------------
__global__ __launch_bounds__(256) void prep_gather_scan(
    const float* __restrict__ W1,
    const float* __restrict__ span,
    const int*   __restrict__ lidx,
    const int*   __restrict__ clens,
    unsigned short* __restrict__ W1sT,
    unsigned short* __restrict__ w1ef,
    unsigned short* __restrict__ A16,
    int*            __restrict__ off)      // [4097], off[4096] = total
{
    const int bid = blockIdx.x, tid = threadIdx.x;

    if (bid == 4432) {   // scan block
        __shared__ int ls[256];
        int myl[16];
        int msum = 0;
#pragma unroll
        for (int j = 0; j < 16; ++j) {
            int bk = tid * 16 + j;
            size_t base = (size_t)(bk >> 11) * NN + lidx[bk];
            int len = clens[base];
            len = len < 0 ? 0 : (len > CC ? CC : len);
            myl[j] = len; msum += len;
        }
        ls[tid] = msum;
        __syncthreads();
        for (int d = 1; d < 256; d <<= 1) {
            int v = (tid >= d) ? ls[tid - d] : 0;
            __syncthreads();
            ls[tid] += v;
            __syncthreads();
        }
        int run = ls[tid] - msum;   // exclusive prefix
#pragma unroll
        for (int j = 0; j < 16; ++j) { off[tid * 16 + j] = run; run += myl[j]; }
        if (tid == 255) off[4096] = run;
        return;
    }
    if (bid >= 336) {    // span gather
        const int bk = bid - 336;
        const float* src = span + ((size_t)(bk >> 11) * NN + lidx[bk]) * DSP;
        float4 x = *(const float4*)(src + tid * 8);
        float4 y = *(const float4*)(src + tid * 8 + 4);
        pack8(&A16[(size_t)bk * DSP + tid * 8], x, y);
        return;
    }
    if (bid < 256) {     // W1 span-part transpose
        __shared__ float t[64][65];
        const int k0 = (bid >> 3) * 64, n0 = (bid & 7) * 64;
#pragma unroll
        for (int p = 0; p < 16; ++p) {
            int flat = p * 256 + tid;
            int r = flat >> 6, c = flat & 63;
            t[r][c] = W1[(size_t)(k0 + r) * HD + n0 + c];
        }
        __syncthreads();
#pragma unroll
        for (int p = 0; p < 16; ++p) {
            int flat = p * 256 + tid;
            int c = flat >> 6, r = flat & 63;
            W1sT[(size_t)(n0 + c) * DSP + k0 + r] = f2bf(t[r][c]);
        }
    } else {             // entity-weight fragments
        int t0 = (bid - 256) * 256 + tid;   // 0..20479
        int lane = t0 & 63;
        int ks = (t0 >> 6) % 10;
        int ncg = (t0 >> 6) / 10;
        int col = ncg * 16 + (lane & 15);
        int kb = ks * 32 + ((lane >> 4) << 3);
        unsigned short v[8];
#pragma unroll
        for (int j = 0; j < 8; ++j) {
            int k = kb + j;
            v[j] = (k < ED) ? f2bf(W1[(size_t)(DSP + k) * HD + col]) : (unsigned short)0;
        }
        *(short8*)&w1ef[(size_t)t0 * 8] = *(short8*)v;
    }
}

// ---------------------------------------------------------------------------
// Kernel 2: span GEMM (bid < 512) + compaction fill (bid >= 512).
// 4-deep LDS pipeline, counted vmcnt. (exact R9)
// ---------------------------------------------------------------------------
__global__ __launch_bounds__(256) void gemm_and_fill(
    const unsigned short* __restrict__ A16,   // [4096][2048] bf16
    const unsigned short* __restrict__ BT,    // [512][2048]  bf16
    const float* __restrict__ b1,
    unsigned short* __restrict__ Cout,        // [4096][512] bf16 (+b1)
    const int* __restrict__ lidx,
    const int* __restrict__ cands,
    const int* __restrict__ clens,
    const int* __restrict__ off,
    int* __restrict__ compact_cand,
    int* __restrict__ compact_meta)
{
    const int tid = threadIdx.x;

    if (blockIdx.x >= 512) {     // ---- fill path ----
        int fb = blockIdx.x - 512;
        int item0 = (fb * 256 + tid) * 4;
#pragma unroll
        for (int q = 0; q < 4; ++q) {
            int item = item0 + q;
            int bk = item >> 4, c = item & 15;
            size_t base = (size_t)(bk >> 11) * NN + lidx[bk];
            int len = clens[base];
            len = len > CC ? CC : len;
            if (c < len) {
                int pos = off[bk] + c;
                compact_cand[pos] = cands[base * CC + c];
                compact_meta[pos] = item;   // (bk<<4)|c
            }
        }
        return;
    }

    // ---- GEMM path ----
    __shared__ __align__(16) unsigned short As[4][64 * 64];   // 32 KB
    __shared__ __align__(16) unsigned short Bs[4][64 * 64];   // 32 KB
    const int l = tid & 63, wid = tid >> 6;
    const int wr = (wid >> 1) * 32, wc = (wid & 1) * 32;

    const int bid = blockIdx.x;
    const int brow = ((bid & 7) * 8 + ((bid >> 3) >> 3)) * 64;
    const int bcol = (((bid >> 3) & 7)) * 64;

    const int s0 = tid, s1 = tid + 256;
    const int r0 = s0 >> 3, c0 = ((s0 & 7) ^ (r0 & 7)) * 8;
    const int r1 = s1 >> 3, c1 = ((s1 & 7) ^ (r1 & 7)) * 8;
    const unsigned short* ga0 = A16 + (size_t)(brow + r0) * DSP + c0;
    const unsigned short* ga1 = A16 + (size_t)(brow + r1) * DSP + c1;
    const unsigned short* gb0 = BT + (size_t)(bcol + r0) * DSP + c0;
    const unsigned short* gb1 = BT + (size_t)(bcol + r1) * DSP + c1;

    int offA[2][2], offB[2][2];
#pragma unroll
    for (int mf = 0; mf < 2; ++mf) {
        int row = wr + mf * 16 + (l & 15);
#pragma unroll
        for (int kk = 0; kk < 2; ++kk)
            offA[mf][kk] = row * 64 + (((kk * 4) + (l >> 4)) ^ (row & 7)) * 8;
    }
#pragma unroll
    for (int nf = 0; nf < 2; ++nf) {
        int row = wc + nf * 16 + (l & 15);
#pragma unroll
        for (int kk = 0; kk < 2; ++kk)
            offB[nf][kk] = row * 64 + (((kk * 4) + (l >> 4)) ^ (row & 7)) * 8;
    }

    f32x4 z = {0.f, 0.f, 0.f, 0.f};
    f32x4 acc[2][2] = {{z, z}, {z, z}};

    auto stage = [&](int buf, int t) {
        const int k0 = t * 64;
        gl_lds16(ga0 + k0, &As[buf][s0 * 8]);
        gl_lds16(ga1 + k0, &As[buf][s1 * 8]);
        gl_lds16(gb0 + k0, &Bs[buf][s0 * 8]);
        gl_lds16(gb1 + k0, &Bs[buf][s1 * 8]);
    };

    auto compute = [&](int buf) {
        short8 am[2][2], bn[2][2];
#pragma unroll
        for (int mf = 0; mf < 2; ++mf)
#pragma unroll
            for (int kk = 0; kk < 2; ++kk)
                am[mf][kk] = *(const short8*)&As[buf][offA[mf][kk]];
#pragma unroll
        for (int nf = 0; nf < 2; ++nf)
#pragma unroll
            for (int kk = 0; kk < 2; ++kk)
                bn[nf][kk] = *(const short8*)&Bs[buf][offB[nf][kk]];
#pragma unroll
        for (int m = 0; m < 2; ++m)
#pragma unroll
            for (int n = 0; n < 2; ++n)
#pragma unroll
                for (int kk = 0; kk < 2; ++kk)
                    acc[m][n] = MFMA16(am[m][kk], bn[n][kk], acc[m][n]);
    };

    stage(0, 0);
    stage(1, 1);
    stage(2, 2);

    for (int t = 0; t < 29; ++t) {
        asm volatile("s_waitcnt vmcnt(8)" ::: "memory");
        __builtin_amdgcn_s_barrier();
        stage((t + 3) & 3, t + 3);
        compute(t & 3);
    }
    asm volatile("s_waitcnt vmcnt(8)" ::: "memory");
    __builtin_amdgcn_s_barrier();
    compute(29 & 3);
    asm volatile("s_waitcnt vmcnt(4)" ::: "memory");
    __builtin_amdgcn_s_barrier();
    compute(30 & 3);
    asm volatile("s_waitcnt vmcnt(0)" ::: "memory");
    __builtin_amdgcn_s_barrier();
    compute(31 & 3);

#pragma unroll
    for (int n = 0; n < 2; ++n) {
        int col = bcol + wc + n * 16 + (l & 15);
        float b1v = b1[col];
#pragma unroll
        for (int m = 0; m < 2; ++m) {
            int row0 = brow + wr + m * 16 + (l >> 4) * 4;
#pragma unroll
            for (int r = 0; r < 4; ++r)
                Cout[(size_t)(row0 + r) * HD + col] = f2bf(acc[m][n][r] + b1v);
        }
    }
}

// ---------------------------------------------------------------------------
// Kernel 3: compacted entity MFMA + fused ReLU/W2/BCE epilogue. (exact R9)
// ---------------------------------------------------------------------------
__global__ __launch_bounds__(512) void ent_mfma(
    const unsigned short* __restrict__ w1ef,
    const unsigned short* __restrict__ span_part,  // [4096][512] bf16 (+b1)
    const float* __restrict__ emb,        // [V][300] f32
    const float* __restrict__ W2,         // [512]
    const float* __restrict__ b2,         // [1]
    const int*   __restrict__ lidx,       // [B*K]
    const float* __restrict__ targets,    // [B*N*16]
    const int*   __restrict__ compact_cand,
    const int*   __restrict__ compact_meta,
    const int*   __restrict__ off,        // off[4096] = total
    float* __restrict__ blockPartial)     // [512]
{
    const int total = off[4096];
    const int bid = blockIdx.x;
    const int slotBase = bid * 128;
    const int tid = threadIdx.x;
    if (slotBase >= total) {
        if (tid == 0) blockPartial[bid] = 0.f;
        return;
    }

    __shared__ __align__(16) unsigned short As[2][8 * 64 * 8];  // 16 KB
    __shared__ float shp[8][16][8];                             // 4 KB
    __shared__ int   meta_s[128];
    __shared__ float wred[8];
    const int wid = tid >> 6, l = tid & 63;

    if (tid < 128) {
        int slot = slotBase + tid;
        meta_s[tid] = (slot < total) ? compact_meta[slot] : -1;
    }

    // staging identity: slot-in-tile = l&15, k-chunk = (l>>4)*8, tile = wid
    const int slot_s = slotBase + wid * 16 + (l & 15);
    const int cid = (slot_s < total) ? compact_cand[slot_s] : 0;
    const float* erow = emb + (size_t)cid * ED;
    const int kb = (l >> 4) * 8;
    const int ht = wid;

    // prologue: ks=0
    float4 lx = *(const float4*)(erow + kb);
    float4 ly = *(const float4*)(erow + kb + 4);
    pack8(&As[0][tid * 8], lx, ly);
    __syncthreads();

    f32x4 z = {0.f, 0.f, 0.f, 0.f};
    f32x4 acc[8][4];
#pragma unroll
    for (int g = 0; g < 8; ++g)
#pragma unroll
        for (int nc = 0; nc < 4; ++nc) acc[g][nc] = z;

    int cur = 0;
    for (int ks = 0; ks < 10; ++ks) {
        const bool pf = (ks < 9);
        if (pf) {   // T14 issue-early
            int k = (ks + 1) * 32 + kb;
            if (k + 8 <= ED) {
                lx = *(const float4*)(erow + k);
                ly = *(const float4*)(erow + k + 4);
            } else {
                float tmp[8];
#pragma unroll
                for (int j = 0; j < 8; ++j) tmp[j] = (k + j < ED) ? erow[k + j] : 0.f;
                lx = make_float4(tmp[0], tmp[1], tmp[2], tmp[3]);
                ly = make_float4(tmp[4], tmp[5], tmp[6], tmp[7]);
            }
        }
        short8 af[8];
#pragma unroll
        for (int g = 0; g < 8; ++g)
            af[g] = *(const short8*)&As[cur][(g * 64 + l) * 8];
#pragma unroll
        for (int nc = 0; nc < 4; ++nc) {
            short8 bf = *(const short8*)&w1ef[(((size_t)(ht * 4 + nc) * 10 + ks) * 64 + l) * 8];
#pragma unroll
            for (int g = 0; g < 8; ++g)
                acc[g][nc] = MFMA16(af[g], bf, acc[g][nc]);
        }
        if (pf) {   // write-late
            pack8(&As[cur ^ 1][tid * 8], lx, ly);
        }
        __syncthreads();
        cur ^= 1;
    }

    // epilogue: relu(acc + span_h[bk(slot)]) . W2, 16-lane reduce
    float w2v[4];
#pragma unroll
    for (int nc = 0; nc < 4; ++nc) w2v[nc] = W2[ht * 64 + nc * 16 + (l & 15)];
    const int rq = (l >> 4) * 4;

#pragma unroll
    for (int g = 0; g < 8; ++g) {
        int bkR[4];
#pragma unroll
        for (int i = 0; i < 4; ++i) {
            int m = meta_s[g * 16 + rq + i];
            bkR[i] = (m >= 0) ? (m >> 4) : 0;
        }
        float s[4] = {0.f, 0.f, 0.f, 0.f};
#pragma unroll
        for (int nc = 0; nc < 4; ++nc) {
            int col = ht * 64 + nc * 16 + (l & 15);
            f32x4 a = acc[g][nc];
#pragma unroll
            for (int i = 0; i < 4; ++i) {
                float sp = bf2f(span_part[(size_t)bkR[i] * HD + col]);
                s[i] += fmaxf(a[i] + sp, 0.f) * w2v[nc];
            }
        }
#pragma unroll
        for (int m = 1; m < 16; m <<= 1) {
#pragma unroll
            for (int i = 0; i < 4; ++i) s[i] += __shfl_xor(s[i], m, 64);
        }
        if ((l & 15) == 0) {
#pragma unroll
            for (int i = 0; i < 4; ++i) shp[g][rq + i][ht] = s[i];
        }
    }
    __syncthreads();

    // fused BCE: 128 threads own one compacted slot each
    float val = 0.f;
    if (tid < 128) {
        int m = meta_s[tid];
        if (m >= 0) {
            int bk = m >> 4, c = m & 15;
            size_t base = (size_t)(bk >> 11) * NN + lidx[bk];
            const float* p = &shp[tid >> 4][tid & 15][0];
            float sc = ((p[0] + p[1]) + (p[2] + p[3])) +
                       ((p[4] + p[5]) + (p[6] + p[7])) + b2[0];
            float tg = targets[base * CC + c];
            val = fmaxf(sc, 0.f) + log1pf(expf(-fabsf(sc))) - sc * tg;
        }
    }
#pragma unroll
    for (int m = 32; m; m >>= 1) val += __shfl_xor(val, m, 64);
    if (l == 0) wred[wid] = val;
    __syncthreads();
    if (tid == 0) {
        float s = 0.f;
#pragma unroll
        for (int w = 0; w < 8; ++w) s += wred[w];
        blockPartial[bid] = s;
    }
}

// ---------------------------------------------------------------------------
// Kernel 4: final deterministic reduce of 512 block partials (exact R9)
// ---------------------------------------------------------------------------
__global__ __launch_bounds__(256) void final_reduce(
    const float* __restrict__ bp, float* __restrict__ out)
{
    __shared__ float red[4];
    float s = bp[threadIdx.x] + bp[threadIdx.x + 256];
#pragma unroll
    for (int m = 32; m; m >>= 1) s += __shfl_xor(s, m, 64);
    if ((threadIdx.x & 63) == 0) red[threadIdx.x >> 6] = s;
    __syncthreads();
    if (threadIdx.x == 0)
        out[0] = (red[0] + red[1]) + (red[2] + red[3]);   // WEIGHT = 1.0
}

// ---------------------------------------------------------------------------
extern "C" void kernel_launch(void* const* d_in, const int* in_sizes, int n_in,
                              void* d_out, int out_size, void* d_ws, size_t ws_size,
                              hipStream_t stream) {
    const float* span    = (const float*)d_in[0];
    const float* targets = (const float*)d_in[1];
    const float* emb     = (const float*)d_in[2];
    const float* W1      = (const float*)d_in[3];
    const float* b1      = (const float*)d_in[4];
    const float* W2      = (const float*)d_in[5];
    const float* b2      = (const float*)d_in[6];
    const int*   lidx    = (const int*)d_in[7];
    const int*   cands   = (const int*)d_in[8];
    const int*   clens   = (const int*)d_in[9];

    char* ws = (char*)d_ws;
    unsigned short* W1sT      = (unsigned short*)(ws);             // 2 MB
    unsigned short* w1ef      = (unsigned short*)(ws + 2097152);   // 320 KB
    unsigned short* A16       = (unsigned short*)(ws + 2424832);   // 16 MB
    unsigned short* span_part = (unsigned short*)(ws + 19202048);  // 4 MB bf16
    int*            off       = (int*)(ws + 23396352);             // 16.4 KB
    int*            ccand     = (int*)(ws + 23412740);             // 256 KB
    int*            cmeta     = (int*)(ws + 23674884);             // 256 KB
    float*          bpart     = (float*)(ws + 23937028);           // 2 KB

    prep_gather_scan<<<4433, 256, 0, stream>>>(W1, span, lidx, clens,
                                               W1sT, w1ef, A16, off);
    gemm_and_fill<<<576, 256, 0, stream>>>(A16, W1sT, b1, span_part,
                                           lidx, cands, clens, off, ccand, cmeta);
    ent_mfma<<<512, 512, 0, stream>>>(w1ef, span_part, emb, W2, b2,
                                      lidx, targets, ccand, cmeta, off, bpart);
    final_reduce<<<1, 256, 0, stream>>>(bpart, (float*)d_out);
}